// Round 5
// baseline (844.756 us; speedup 1.0000x reference)
//
#include <hip/hip_runtime.h>

#define SPATIAL 32768
#define BATCH   4
#define CH      256
#define KCODES  1024
#define NPTS    (BATCH*SPATIAL)          // 131072
#define ZQ_SIZE (BATCH*CH*SPATIAL)       // 33554432

// workspace layout (bytes)
#define WS_LOSS  0                        // double
#define WS_CNT   8                        // int
#define WS_ENORM 16                       // float[1024] -> ends 4112
#define WS_EHP   4352                     // f16 frag-packed [64kb][8cc][64lane][8j]
#define WS_ELP   (WS_EHP + KCODES*CH*2)   // 528640
#define WS_FLAGS (WS_ELP + KCODES*CH*2)   // int[NPTS]

#define MARG 1.5e-4f  // covers split err + MFMA-vs-chain diff + 2 ulp(512)

typedef _Float16 f16x8 __attribute__((ext_vector_type(8)));
typedef float    f32x4 __attribute__((ext_vector_type(4)));

// pack e*1024 into f16 hi/lo in MFMA B-fragment order:
// element (code, ch) -> [kb=code>>4][cc=ch>>5][lane=((ch>>3)&3)*16+(code&15)][j=ch&7]
__global__ __launch_bounds__(256) void vq_prep(const float* __restrict__ emb,
                                               f16x8* __restrict__ ehp,
                                               f16x8* __restrict__ elp) {
  int kb = blockIdx.x;
#pragma unroll
  for (int h = 0; h < 2; ++h) {
    int q = threadIdx.x + h * 256;          // chunk within kb: 0..511
    int cc = q >> 6, ln = q & 63;
    int hq = ln >> 4, lr = ln & 15;
    const float* src = emb + ((size_t)(kb * 16 + lr) * CH + cc * 32 + hq * 8);
    f16x8 h8, l8;
#pragma unroll
    for (int j = 0; j < 8; ++j) {
      float es = src[j] * 1024.0f;
      _Float16 hi = (_Float16)es;
      h8[j] = hi;
      l8[j] = (_Float16)(es - (float)hi);
    }
    ehp[kb * 512 + q] = h8;
    elp[kb * 512 + q] = l8;
  }
}

__global__ __launch_bounds__(256) void vq_enorm(const float* __restrict__ emb,
                                                float* __restrict__ enorm) {
  int k = blockIdx.x * 256 + threadIdx.x;
  const float* e = emb + (size_t)k * CH;
  double s = 0.0;
#pragma unroll 8
  for (int c = 0; c < CH; ++c) s = fma((double)e[c], (double)e[c], s);
  enorm[k] = (float)s;
}

// 2048 blocks x 256 thr; block = 64 points x all 1024 codes, f16-split MFMA.
// All LDS/global fragment accesses are linear (base + lane*16): conflict-free.
__global__ __launch_bounds__(256, 2) void vq_main(
    const float* __restrict__ z, const f16x8* __restrict__ ehp,
    const f16x8* __restrict__ elp, const float* __restrict__ enorm,
    float* __restrict__ out_idx, double* __restrict__ loss_acc,
    int* __restrict__ flag_cnt, int* __restrict__ flags) {
  __shared__ f16x8 zfrag[64][64];   // [h*32 + m*8 + cc][lane]  = 64 KB
  __shared__ float en_s[KCODES];
  __shared__ double znp[4][64];
  __shared__ float  znb[64];
  __shared__ float rm1s[4][64];
  __shared__ float rm2s[4][64];
  __shared__ int   ri1s[4][64];

  int tid = threadIdx.x;
  int w = tid >> 6;
  int lane = tid & 63;
  int n0 = blockIdx.x * 64;
  int b = n0 / SPATIAL, s0 = n0 % SPATIAL;
  const float* zb = z + (size_t)b * CH * SPATIAL + s0;

  // stage z as f16 hi/lo directly into fragment order; f64 zn partials
  {
    int pt = lane, m = pt >> 4, lr = pt & 15;
    const float* zcol = zb + pt;
    double zacc = 0.0;
#pragma unroll
    for (int oct = 0; oct < 8; ++oct) {
      int c0 = w * 64 + oct * 8;
      int cc = c0 >> 5, hq = (c0 >> 3) & 3;
      f16x8 h8, l8;
#pragma unroll
      for (int i = 0; i < 8; ++i) {
        float v = zcol[(size_t)(c0 + i) * SPATIAL];
        zacc = fma((double)v, (double)v, zacc);
        _Float16 hh = (_Float16)v;
        h8[i] = hh;
        l8[i] = (_Float16)(v - (float)hh);
      }
      zfrag[m * 8 + cc][hq * 16 + lr] = h8;
      zfrag[32 + m * 8 + cc][hq * 16 + lr] = l8;
    }
    znp[w][pt] = zacc;
  }
#pragma unroll
  for (int j = 0; j < 4; ++j) en_s[tid + 256 * j] = enorm[tid + 256 * j];
  __syncthreads();
  if (tid < 64)
    znb[tid] = (float)(znp[0][tid] + znp[1][tid] + znp[2][tid] + znp[3][tid]);
  __syncthreads();

  int hq = lane >> 4;
  int lr = lane & 15;

  float znr[16];
#pragma unroll
  for (int m = 0; m < 4; ++m)
#pragma unroll
    for (int r = 0; r < 4; ++r) znr[m * 4 + r] = znb[m * 16 + hq * 4 + r];

  float rm1[16], rm2[16];
  int   ri1[16];
#pragma unroll
  for (int q = 0; q < 16; ++q) { rm1[q] = 1e30f; rm2[q] = 1e30f; ri1[q] = 0; }

  for (int kt = 0; kt < 8; ++kt) {
    int kb0 = kt * 8 + w * 2;
    const f16x8* ph0 = ehp + (size_t)kb0 * 512 + lane;
    const f16x8* ph1 = ph0 + 512;
    const f16x8* pl0 = elp + (size_t)kb0 * 512 + lane;
    const f16x8* pl1 = pl0 + 512;

    f32x4 acc[4][2];
#pragma unroll
    for (int m = 0; m < 4; ++m)
#pragma unroll
      for (int n = 0; n < 2; ++n) acc[m][n] = (f32x4){0.f, 0.f, 0.f, 0.f};

    // double-buffered B-fragments: prefetch cc+1 while MFMAing cc
    f16x8 bh[2][2], bl[2][2];
    bh[0][0] = ph0[0]; bh[0][1] = ph1[0];
    bl[0][0] = pl0[0]; bl[0][1] = pl1[0];
#pragma unroll
    for (int cc = 0; cc < 8; ++cc) {
      int cur = cc & 1, nxt = cur ^ 1;
      if (cc < 7) {
        bh[nxt][0] = ph0[(cc + 1) * 64]; bh[nxt][1] = ph1[(cc + 1) * 64];
        bl[nxt][0] = pl0[(cc + 1) * 64]; bl[nxt][1] = pl1[(cc + 1) * 64];
      }
      f16x8 ah[4], al[4];
#pragma unroll
      for (int m = 0; m < 4; ++m) {
        ah[m] = zfrag[m * 8 + cc][lane];
        al[m] = zfrag[32 + m * 8 + cc][lane];
      }
#pragma unroll
      for (int m = 0; m < 4; ++m)
#pragma unroll
        for (int n = 0; n < 2; ++n) {
          acc[m][n] = __builtin_amdgcn_mfma_f32_16x16x32_f16(ah[m], bh[cur][n], acc[m][n], 0, 0, 0);
          acc[m][n] = __builtin_amdgcn_mfma_f32_16x16x32_f16(al[m], bh[cur][n], acc[m][n], 0, 0, 0);
          acc[m][n] = __builtin_amdgcn_mfma_f32_16x16x32_f16(ah[m], bl[cur][n], acc[m][n], 0, 0, 0);
        }
    }

    // fold into per-thread top-2 (D-frag: row = hq*4+r, col = lr)
    float enA = en_s[kt * 128 + w * 32 + lr];
    float enB = en_s[kt * 128 + w * 32 + 16 + lr];
    int c0i = kt * 128 + w * 32 + lr;
#pragma unroll
    for (int m = 0; m < 4; ++m) {
#pragma unroll
      for (int r = 0; r < 4; ++r) {
        int q = m * 4 + r;
        float zn = znr[q];
        float p0 = (zn + enA) - acc[m][0][r] * 0x1p-9f;
        float p1 = (zn + enB) - acc[m][1][r] * 0x1p-9f;
        if (p0 < rm1[q]) { rm2[q] = rm1[q]; rm1[q] = p0; ri1[q] = c0i; }
        else             { rm2[q] = fminf(rm2[q], p0); }
        if (p1 < rm1[q]) { rm2[q] = rm1[q]; rm1[q] = p1; ri1[q] = c0i + 16; }
        else             { rm2[q] = fminf(rm2[q], p1); }
      }
    }
  }

  // one butterfly per row across the 16 lr-lanes
#pragma unroll
  for (int m = 0; m < 4; ++m) {
#pragma unroll
    for (int r = 0; r < 4; ++r) {
      int q = m * 4 + r;
      float m1 = rm1[q], m2 = rm2[q];
      int i1 = ri1[q];
#pragma unroll
      for (int msk = 1; msk <= 8; msk <<= 1) {
        float om1 = __shfl_xor(m1, msk);
        float om2 = __shfl_xor(m2, msk);
        int   oi1 = __shfl_xor(i1, msk);
        if (om1 < m1 || (om1 == m1 && oi1 < i1)) {
          m2 = fminf(m1, om2); m1 = om1; i1 = oi1;
        } else {
          m2 = fminf(m2, om1);
        }
      }
      if (lr == 0) {
        int pt = m * 16 + hq * 4 + r;
        rm1s[w][pt] = m1; rm2s[w][pt] = m2; ri1s[w][pt] = i1;
      }
    }
  }
  __syncthreads();

  if (tid < 64) {
    float m1 = rm1s[0][tid], m2 = rm2s[0][tid];
    int i1 = ri1s[0][tid];
#pragma unroll
    for (int pq = 1; pq < 4; ++pq) {
      float a1 = rm1s[pq][tid], a2 = rm2s[pq][tid];
      int ai = ri1s[pq][tid];
      if (a1 < m1 || (a1 == m1 && ai < i1)) {
        m2 = fminf(m1, a2); m1 = a1; i1 = ai;
      } else {
        m2 = fminf(m2, a1);
      }
    }
    int n = n0 + tid;
    out_idx[n] = (float)i1;
    if (m2 - m1 <= MARG) {
      int p = atomicAdd(flag_cnt, 1);
      if (p < NPTS) flags[p] = n;
    }
    double dv = (double)m1;
#pragma unroll
    for (int msk = 1; msk < 64; msk <<= 1) dv += __shfl_xor(dv, msk);
    if (tid == 0) atomicAdd(loss_acc, dv);
  }
}

// exact numpy-fp32-chain re-decision for flagged points
__global__ __launch_bounds__(256) void vq_recheck(
    const float* __restrict__ z, const float* __restrict__ emb,
    const float* __restrict__ enorm, const int* __restrict__ flag_cnt,
    const int* __restrict__ flags, float* __restrict__ out_idx) {
  __shared__ float zs[4][CH];
  __shared__ float znf[4];
  __shared__ float bm[256];
  __shared__ int   bi[256];
  int cnt = *flag_cnt; if (cnt > NPTS) cnt = NPTS;
  int t = threadIdx.x;
  for (int base = blockIdx.x * 4; base < cnt; base += gridDim.x * 4) {
#pragma unroll
    for (int q = 0; q < 4; ++q) {
      int ii = base + q; if (ii >= cnt) ii = cnt - 1;
      int n = flags[ii];
      int b = n / SPATIAL, s = n % SPATIAL;
      zs[q][t] = z[((size_t)b * CH + t) * SPATIAL + s];
    }
    __syncthreads();
    if (t < 4) {
      double sd = 0.0;
      for (int c = 0; c < CH; ++c) sd = fma((double)zs[t][c], (double)zs[t][c], sd);
      znf[t] = (float)sd;
    }
    __syncthreads();
    float best[4] = {1e30f, 1e30f, 1e30f, 1e30f};
    int besti[4] = {0, 0, 0, 0};
    for (int q = 0; q < 4; ++q) {
      int code = t + 256 * q;
      const float* er = emb + (size_t)code * CH;
      float g0 = 0.f, g1 = 0.f, g2 = 0.f, g3 = 0.f;
#pragma unroll 8
      for (int c = 0; c < CH; ++c) {
        float e = er[c];
        g0 = fmaf(zs[0][c], e, g0);
        g1 = fmaf(zs[1][c], e, g1);
        g2 = fmaf(zs[2][c], e, g2);
        g3 = fmaf(zs[3][c], e, g3);
      }
      float en = enorm[code];
      float d0 = (znf[0] + en) - 2.f * g0;
      float d1 = (znf[1] + en) - 2.f * g1;
      float d2 = (znf[2] + en) - 2.f * g2;
      float d3 = (znf[3] + en) - 2.f * g3;
      if (d0 < best[0]) { best[0] = d0; besti[0] = code; }
      if (d1 < best[1]) { best[1] = d1; besti[1] = code; }
      if (d2 < best[2]) { best[2] = d2; besti[2] = code; }
      if (d3 < best[3]) { best[3] = d3; besti[3] = code; }
    }
#pragma unroll
    for (int p = 0; p < 4; ++p) {
      bm[t] = best[p]; bi[t] = besti[p];
      __syncthreads();
      for (int off = 128; off > 0; off >>= 1) {
        if (t < off) {
          float ob = bm[t + off]; int oi = bi[t + off];
          if (ob < bm[t] || (ob == bm[t] && oi < bi[t])) { bm[t] = ob; bi[t] = oi; }
        }
        __syncthreads();
      }
      int ii = base + p;
      if (t == 0 && ii < cnt) out_idx[flags[ii]] = (float)bi[0];
      __syncthreads();
    }
  }
}

// 64-point blocks: gather each point's emb row ONCE (coalesced) into
// XOR-swizzled LDS, write out transposed coalesced. Also finalize loss.
__global__ __launch_bounds__(256) void vq_scatter(
    const float* __restrict__ emb, const float* __restrict__ out_idx,
    float* __restrict__ zq, const double* __restrict__ loss_acc,
    float* __restrict__ loss_out) {
  __shared__ float rows[64][256];   // rows[s][c ^ (s&31)]
  __shared__ int idxs[64];
  int tid = threadIdx.x;
  int n0 = blockIdx.x * 64;
  int b = n0 / SPATIAL, s0 = n0 % SPATIAL;
  if (tid < 64) idxs[tid] = (int)out_idx[n0 + tid];
  __syncthreads();
  int lane = tid & 63, grp = tid >> 6;
  // gather: wave grp handles rows grp, grp+4, ... (lane = channel strided)
  for (int r = grp; r < 64; r += 4) {
    const float* er = emb + (size_t)idxs[r] * CH;
    int sw = r & 31;
#pragma unroll
    for (int i = 0; i < 4; ++i) {
      int c = lane + 64 * i;
      rows[r][c ^ sw] = er[c];
    }
  }
  __syncthreads();
  // write: per iter, wave grp writes channel c for all 64 s (coalesced 256B)
  for (int it = 0; it < 64; ++it) {
    int c = grp * 64 + it;
    float v = rows[lane][c ^ (lane & 31)];
    zq[((size_t)(b * CH + c)) * SPATIAL + s0 + lane] = v;
  }
  if (blockIdx.x == 0 && tid == 0)
    loss_out[0] = (float)(loss_acc[0] * 1.25 / (double)ZQ_SIZE);
}

extern "C" void kernel_launch(void* const* d_in, const int* in_sizes, int n_in,
                              void* d_out, int out_size, void* d_ws, size_t ws_size,
                              hipStream_t stream) {
  const float* z   = (const float*)d_in[0];
  const float* emb = (const float*)d_in[1];
  float* out = (float*)d_out;
  char* ws = (char*)d_ws;

  double* loss_acc = (double*)(ws + WS_LOSS);
  int*    flag_cnt = (int*)(ws + WS_CNT);
  float*  enorm    = (float*)(ws + WS_ENORM);
  f16x8*  ehp      = (f16x8*)(ws + WS_EHP);
  f16x8*  elp      = (f16x8*)(ws + WS_ELP);
  int*    flags    = (int*)(ws + WS_FLAGS);

  float* loss_out = out + ZQ_SIZE;
  float* out_idx  = out + ZQ_SIZE + 1;

  hipMemsetAsync(d_ws, 0, 16, stream);
  vq_prep<<<KCODES / 16, 256, 0, stream>>>(emb, ehp, elp);
  vq_enorm<<<KCODES / 256, 256, 0, stream>>>(emb, enorm);
  vq_main<<<NPTS / 64, 256, 0, stream>>>(z, ehp, elp, enorm, out_idx,
                                         loss_acc, flag_cnt, flags);
  vq_recheck<<<512, 256, 0, stream>>>(z, emb, enorm, flag_cnt, flags, out_idx);
  vq_scatter<<<NPTS / 64, 256, 0, stream>>>(emb, out_idx, out, loss_acc, loss_out);
}